// Round 1
// baseline (55218.329 us; speedup 1.0000x reference)
//
#include <hip/hip_runtime.h>
#include <stdint.h>

typedef unsigned long long u64;

#define SLEN 8192

// ws layout (u64 units):
//   h0 ring  [4][1024]  @ 0      (layer-0 hidden, tagged (value,step))
//   h1 ring  [2][1024]  @ 4096   (layer-1 hidden)
//   parts    [4][128]   @ 6144   (per-B-CU partial of w_ffn·h1 (+b_ffn in part 0))
#define H0_OFF 0
#define H1_OFF 4096
#define PR_OFF 6144
#define WS_U64 6656

__device__ __forceinline__ u64 ld_agent(u64* p) {
  return __hip_atomic_load(p, __ATOMIC_RELAXED, __HIP_MEMORY_SCOPE_AGENT);
}
__device__ __forceinline__ float poll_val(u64* p, unsigned tag) {
  u64 v = ld_agent(p);
  while ((unsigned)(v >> 32) != tag) {
    __builtin_amdgcn_s_sleep(1);
    v = ld_agent(p);
  }
  return __uint_as_float((unsigned)v);
}
// issue both loads before waiting (overlap the two IC round-trips)
__device__ __forceinline__ float2 poll_pair(u64* p0, u64* p1, unsigned tag) {
  u64 v0 = ld_agent(p0);
  u64 v1 = ld_agent(p1);
  while ((unsigned)(v0 >> 32) != tag) { __builtin_amdgcn_s_sleep(1); v0 = ld_agent(p0); }
  while ((unsigned)(v1 >> 32) != tag) { __builtin_amdgcn_s_sleep(1); v1 = ld_agent(p1); }
  return make_float2(__uint_as_float((unsigned)v0), __uint_as_float((unsigned)v1));
}
__device__ __forceinline__ void pub_val(u64* p, float f, unsigned tag) {
  u64 v = ((u64)tag << 32) | (u64)__float_as_uint(f);
  __hip_atomic_store(p, v, __ATOMIC_RELAXED, __HIP_MEMORY_SCOPE_AGENT);
}
__device__ __forceinline__ float sigm(float v) { return 1.f / (1.f + expf(-v)); }
__device__ __forceinline__ float tanh_f(float v) {
  float e = expf(-2.f * fabsf(v));
  float r = (1.f - e) / (1.f + e);
  return copysignf(r, v);
}

// padded LDS layout for the 1024-float hidden vector: 64 chunks of 16 floats,
// chunk stride 20 floats (80 B) -> ds_read_b128 spreads over all 8 bank groups.
__device__ __forceinline__ int lds_idx(int k) { return (k >> 4) * 20 + (k & 15); }

__global__ __launch_bounds__(512, 2) void lstm_pipe(
    const float* __restrict__ x, const int* __restrict__ mask,
    const float* __restrict__ feat, const int* __restrict__ tfp,
    const float* __restrict__ w_ih0, const float* __restrict__ w_hh0,
    const float* __restrict__ b_ih0, const float* __restrict__ b_hh0,
    const float* __restrict__ w_ih1, const float* __restrict__ w_hh1,
    const float* __restrict__ b_ih1, const float* __restrict__ b_hh1,
    const float* __restrict__ w_ffn, const float* __restrict__ b_ffn,
    float* __restrict__ out, u64* __restrict__ ws)
{
  u64* h0r = ws + H0_OFF;
  u64* h1r = ws + H1_OFF;
  u64* pr  = ws + PR_OFF;
  const int tid  = threadIdx.x;
  const int lane = tid & 63;
  const int wv   = tid >> 6;          // wave id 0..7
  const bool tf1 = (*tfp) >= 1;       // teacher_force_ratio >= 1

  __shared__ __align__(16) float lh0[2][1280];
  __shared__ __align__(16) float lh1[2][1280];
  __shared__ float lpart[8];
  __shared__ float lys;

  if (blockIdx.x < 128) {
    // ================= layer-0 CU: owns h0 outputs m = 8*blk + wave =================
    const int m = blockIdx.x * 8 + wv;
    float4 wh[4][4];                  // W_hh0 rows {m+1024g}, k in [16*lane, 16*lane+16)
#pragma unroll
    for (int g = 0; g < 4; ++g) {
      const float4* s = reinterpret_cast<const float4*>(
          w_hh0 + (size_t)(m + 1024 * g) * 1024 + lane * 16);
#pragma unroll
      for (int u = 0; u < 4; ++u) wh[g][u] = s[u];
    }
    // lane<16: w_ih0 column 'lane'; lane==16: fused bias; else 0
    float wf[4];
#pragma unroll
    for (int g = 0; g < 4; ++g) {
      int row = m + 1024 * g;
      wf[g] = (lane < 16) ? w_ih0[row * 16 + lane]
            : (lane == 16 ? (b_ih0[row] + b_hh0[row]) : 0.f);
    }
    float c0 = 0.f;

    for (int t = 0; t < SLEN; ++t) {
      // per-step inputs (cached loads, independent of the ring polls)
      const bool use_x = (t == 0) || (tf1 && mask[t] != 0);
      float base_in;
      if (lane == 0)       base_in = use_x ? x[t] : 0.f;   // y-term added later if !use_x
      else if (lane < 16)  base_in = feat[t * 15 + (lane - 1)];
      else if (lane == 16) base_in = 1.f;                  // bias slot
      else                 base_in = 0.f;

      if (t > 0) {  // stage h0[t-1] -> LDS (512 threads x 2 entries)
        const int q = t - 1, s4 = q & 3, sp = q & 1;
        const int k0 = tid * 2;
        float2 f2 = poll_pair(&h0r[s4 * 1024 + k0], &h0r[s4 * 1024 + k0 + 1], (unsigned)q);
        *reinterpret_cast<float2*>(&lh0[sp][lds_idx(k0)]) = f2;
      }
      float acc[4];
#pragma unroll
      for (int g = 0; g < 4; ++g) acc[g] = wf[g] * base_in;
      __syncthreads();

      if (t > 0) {  // W_hh0 · h0[t-1]
        const float4* hv = reinterpret_cast<const float4*>(&lh0[(t - 1) & 1][lane * 20]);
#pragma unroll
        for (int u = 0; u < 4; ++u) {
          float4 h4 = hv[u];
#pragma unroll
          for (int g = 0; g < 4; ++g)
            acc[g] += wh[g][u].x * h4.x + wh[g][u].y * h4.y +
                      wh[g][u].z * h4.z + wh[g][u].w * h4.w;
        }
      }
#pragma unroll
      for (int off = 1; off < 64; off <<= 1) {
#pragma unroll
        for (int g = 0; g < 4; ++g) acc[g] += __shfl_xor(acc[g], off, 64);
      }

      const bool need_y = (t > 0) && !use_x;
      if (need_y) {
        // y[t-1] = sum of 128 published partials (b_ffn folded into part 0)
        if (wv == 0) {
          const int s4 = (t - 1) & 3;
          float2 p2 = poll_pair(&pr[s4 * 128 + lane], &pr[s4 * 128 + 64 + lane],
                                (unsigned)(t - 1));
          float s = p2.x + p2.y;
#pragma unroll
          for (int off = 1; off < 64; off <<= 1) s += __shfl_xor(s, off, 64);
          if (lane == 0) lys = s;
        }
        __syncthreads();
        if (lane == 0) {
          float y = lys;
#pragma unroll
          for (int g = 0; g < 4; ++g) acc[g] += y * wf[g];  // lane0's wf == w_ih0[:,0]
        }
      } else if (t >= 3) {
        // flow control: confirm all B CUs finished step t-3 before overwriting
        // the depth-4 h0 ring slot (prevents A running >3 steps ahead of B)
        if (wv == 0) {
          const int s4 = (t - 3) & 3;
          (void)poll_pair(&pr[s4 * 128 + lane], &pr[s4 * 128 + 64 + lane],
                          (unsigned)(t - 3));
        }
        __syncthreads();
      }

      if (lane == 0) {  // gates (torch order i,f,g,o) and publish
        float ii = sigm(acc[0]);
        float ff = sigm(acc[1]);
        float gg = tanh_f(acc[2]);
        float oo = sigm(acc[3]);
        c0 = ff * c0 + ii * gg;
        float h = oo * tanh_f(c0);
        pub_val(&h0r[(t & 3) * 1024 + m], h, (unsigned)t);
      }
    }
  } else {
    // ================= layer-1 CU: owns h1 outputs m = 8*(blk-128) + wave =================
    const int b = blockIdx.x - 128;
    const int m = b * 8 + wv;
    float4 wi[4][4], wh[4][4];
#pragma unroll
    for (int g = 0; g < 4; ++g) {
      const float4* si = reinterpret_cast<const float4*>(
          w_ih1 + (size_t)(m + 1024 * g) * 1024 + lane * 16);
      const float4* sh = reinterpret_cast<const float4*>(
          w_hh1 + (size_t)(m + 1024 * g) * 1024 + lane * 16);
#pragma unroll
      for (int u = 0; u < 4; ++u) { wi[g][u] = si[u]; wh[g][u] = sh[u]; }
    }
    float bb[4];
#pragma unroll
    for (int g = 0; g < 4; ++g) {
      int row = m + 1024 * g;
      bb[g] = (lane == 16) ? (b_ih1[row] + b_hh1[row]) : 0.f;
    }
    const float wffn = (lane == 0) ? w_ffn[m] : 0.f;
    const float bf = b_ffn[0];
    float c1 = 0.f;

    for (int t = 0; t < SLEN; ++t) {
      if (t > 0) {  // stage h1[t-1]
        const int q = t - 1, sp = q & 1;
        const int k0 = tid * 2;
        float2 f2 = poll_pair(&h1r[sp * 1024 + k0], &h1r[sp * 1024 + k0 + 1], (unsigned)q);
        *reinterpret_cast<float2*>(&lh1[sp][lds_idx(k0)]) = f2;
      }
      {  // stage h0[t] (the critical-path arrival)
        const int s4 = t & 3, sp = t & 1;
        const int k0 = tid * 2;
        float2 f2 = poll_pair(&h0r[s4 * 1024 + k0], &h0r[s4 * 1024 + k0 + 1], (unsigned)t);
        *reinterpret_cast<float2*>(&lh0[sp][lds_idx(k0)]) = f2;
      }
      float acc[4];
#pragma unroll
      for (int g = 0; g < 4; ++g) acc[g] = bb[g];
      __syncthreads();

      {  // W_ih1 · h0[t]
        const float4* hv = reinterpret_cast<const float4*>(&lh0[t & 1][lane * 20]);
#pragma unroll
        for (int u = 0; u < 4; ++u) {
          float4 h4 = hv[u];
#pragma unroll
          for (int g = 0; g < 4; ++g)
            acc[g] += wi[g][u].x * h4.x + wi[g][u].y * h4.y +
                      wi[g][u].z * h4.z + wi[g][u].w * h4.w;
        }
      }
      if (t > 0) {  // W_hh1 · h1[t-1]
        const float4* hv = reinterpret_cast<const float4*>(&lh1[(t - 1) & 1][lane * 20]);
#pragma unroll
        for (int u = 0; u < 4; ++u) {
          float4 h4 = hv[u];
#pragma unroll
          for (int g = 0; g < 4; ++g)
            acc[g] += wh[g][u].x * h4.x + wh[g][u].y * h4.y +
                      wh[g][u].z * h4.z + wh[g][u].w * h4.w;
        }
      }
#pragma unroll
      for (int off = 1; off < 64; off <<= 1) {
#pragma unroll
        for (int g = 0; g < 4; ++g) acc[g] += __shfl_xor(acc[g], off, 64);
      }

      if (lane == 0) {
        float ii = sigm(acc[0]);
        float ff = sigm(acc[1]);
        float gg = tanh_f(acc[2]);
        float oo = sigm(acc[3]);
        c1 = ff * c1 + ii * gg;
        float h = oo * tanh_f(c1);
        pub_val(&h1r[(t & 1) * 1024 + m], h, (unsigned)t);
        lpart[wv] = wffn * h;
      }
      __syncthreads();
      if (tid == 0) {
        float s = lpart[0] + lpart[1] + lpart[2] + lpart[3] +
                  lpart[4] + lpart[5] + lpart[6] + lpart[7];
        if (b == 0) s += bf;                       // fold b_ffn into part 0
        pub_val(&pr[(t & 3) * 128 + b], s, (unsigned)t);
        atomicAdd(&out[t], s);                     // off critical path; |order noise| ~1e-7
      }
    }
  }
}

extern "C" void kernel_launch(void* const* d_in, const int* in_sizes, int n_in,
                              void* d_out, int out_size, void* d_ws, size_t ws_size,
                              hipStream_t stream) {
  (void)in_sizes; (void)n_in; (void)out_size; (void)ws_size;
  const float* x      = (const float*)d_in[0];
  const int*   mask   = (const int*)  d_in[1];
  const float* feat   = (const float*)d_in[2];
  const int*   tfp    = (const int*)  d_in[3];
  const float* w_ih0  = (const float*)d_in[4];
  const float* w_hh0  = (const float*)d_in[5];
  const float* b_ih0  = (const float*)d_in[6];
  const float* b_hh0  = (const float*)d_in[7];
  const float* w_ih1  = (const float*)d_in[8];
  const float* w_hh1  = (const float*)d_in[9];
  const float* b_ih1  = (const float*)d_in[10];
  const float* b_hh1  = (const float*)d_in[11];
  const float* w_ffn  = (const float*)d_in[12];
  const float* b_ffn  = (const float*)d_in[13];
  float* out = (float*)d_out;
  u64*   ws  = (u64*)d_ws;

  // invalidate ring tags (0xFFFFFFFF never equals a step index) and zero output
  hipMemsetAsync(d_ws, 0xFF, (size_t)WS_U64 * sizeof(u64), stream);
  hipMemsetAsync(d_out, 0, (size_t)SLEN * sizeof(float), stream);

  lstm_pipe<<<dim3(256), dim3(512), 0, stream>>>(
      x, mask, feat, tfp, w_ih0, w_hh0, b_ih0, b_hh0,
      w_ih1, w_hh1, b_ih1, b_hh1, w_ffn, b_ffn, out, ws);
}